// Round 10
// baseline (533.508 us; speedup 1.0000x reference)
//
#include <hip/hip_runtime.h>
#include <math.h>

typedef __attribute__((ext_vector_type(4))) float f32x4;
typedef __bf16 bf16x8 __attribute__((ext_vector_type(8)));

#define LOG_2PI_F 1.8378770664093453f

// scal layout (ints): [0]=cnt0 [1]=cnt1 [4]=base1 [5]=mact [6]=mpad

__device__ static inline ushort f2bf(float f) {
    union { float f; unsigned u; } c; c.f = f;
    unsigned u = c.u;
    unsigned r = (u + 0x7FFFu + ((u >> 16) & 1u)) >> 16;
    return (ushort)r;
}
__device__ static inline float bf2f(ushort h) {
    union { unsigned u; float f; } c; c.u = ((unsigned)h) << 16;
    return c.f;
}

// ================= fused prep (round-9 verified) =================
__global__ __launch_bounds__(256) void prep_all(
    const float* __restrict__ obs, const int* __restrict__ role_ids,
    const float* __restrict__ W0, const float* __restrict__ W1,
    const float* __restrict__ W2, const float* __restrict__ hW1,
    const float* __restrict__ hW2,
    ushort* __restrict__ obsb, ushort* __restrict__ W0t, ushort* __restrict__ W1t,
    ushort* __restrict__ W2t, ushort* __restrict__ hW1t, ushort* __restrict__ hW2t,
    int* __restrict__ slot2tok, int* __restrict__ scal, float* __restrict__ out) {
    __shared__ float tile[32][33];
    __shared__ int sh[16];
    __shared__ int s_of[256];
    const int tid = threadIdx.x;
    const int id = blockIdx.x;

    if (id < 128) {
        const int b = id;
        const int lane = tid & 63, w = tid >> 6;
        const int limit = b << 8;  // b*256
        int pre0 = 0, pre1 = 0, tot0 = 0, tot1 = 0;
        for (int g = 0; g < 128; g++) {
            int i = (w << 13) + (g << 6) + lane;
            int r = role_ids[i];
            int c0 = (int)__popcll(__ballot(r == 0));
            int c1 = (int)__popcll(__ballot(r == 1));
            int gs = (w << 13) + (g << 6);
            if (gs < limit) { pre0 += c0; pre1 += c1; }
            tot0 += c0; tot1 += c1;
        }
        if (lane == 0) { sh[w] = pre0; sh[4 + w] = pre1; sh[8 + w] = tot0; sh[12 + w] = tot1; }
        __syncthreads();
        const int preA0 = sh[0] + sh[1] + sh[2] + sh[3];
        const int preA1 = sh[4] + sh[5] + sh[6] + sh[7];
        const int totA0 = sh[8] + sh[9] + sh[10] + sh[11];
        const int totA1 = sh[12] + sh[13] + sh[14] + sh[15];
        __syncthreads();
        const int base1 = (totA0 + 127) & ~127;
        if (b == 0 && tid == 0) {
            int mact = base1 + totA1;
            scal[0] = totA0; scal[1] = totA1;
            scal[4] = base1; scal[5] = mact; scal[6] = (mact + 127) & ~127;
        }
        const int i = (b << 8) + tid;
        const int r = role_ids[i];
        unsigned long long b0 = __ballot(r == 0);
        unsigned long long b1 = __ballot(r == 1);
        if (lane == 0) { sh[w] = (int)__popcll(b0); sh[4 + w] = (int)__popcll(b1); }
        __syncthreads();
        int w0 = 0, w1 = 0;
        for (int j = 0; j < 4; j++) if (j < w) { w0 += sh[j]; w1 += sh[4 + j]; }
        unsigned long long lt = (lane == 0) ? 0ull
                             : ((lane == 63) ? 0x7FFFFFFFFFFFFFFFull : ((1ull << lane) - 1));
        int slot = -1;
        if (r == 0)      slot = preA0 + w0 + (int)__popcll(b0 & lt);
        else if (r == 1) slot = base1 + preA1 + w1 + (int)__popcll(b1 & lt);
        if (slot >= 0) slot2tok[slot] = i;
        else           out[i] = 0.f;
        s_of[tid] = slot;
        __syncthreads();
        for (int rr = w; rr < 256; rr += 4) {
            int s = s_of[rr];
            if (s < 0) continue;
            float2 v = ((const float2*)(obs + (size_t)(limit + rr) * 128))[lane];
            ((ushort2*)(obsb + (size_t)s * 128))[lane] = (ushort2){f2bf(v.x), f2bf(v.y)};
        }
        return;
    }

    int tix = id - 128;
    const float* in; ushort* outp; int R, C, t;
    if (tix < 1024)      { in = W1;             outp = W1t;             R = 1024; C = 1024; t = tix; }
    else if (tix < 2048) { in = W2;             outp = W2t;             R = 1024; C = 1024; t = tix - 1024; }
    else if (tix < 2560) { in = hW1;            outp = hW1t;            R = 1024; C = 512;  t = tix - 2048; }
    else if (tix < 3072) { in = hW1 + 1024*512; outp = hW1t + 512*1024; R = 1024; C = 512;  t = tix - 2560; }
    else if (tix < 3200) { in = W0;             outp = W0t;             R = 128;  C = 1024; t = tix - 3072; }
    else if (tix < 3216) { in = hW2;            outp = hW2t;            R = 512;  C = 8;    t = tix - 3200; }
    else                 { in = hW2 + 512*8;    outp = hW2t + 8*512;    R = 512;  C = 8;    t = tix - 3216; }
    const int tx = tid & 31, ty = tid >> 5;
    int tX = (C + 31) >> 5;
    int c0 = (t % tX) << 5, r0 = (t / tX) << 5;
    for (int j = ty; j < 32; j += 8) {
        int r = r0 + j, c = c0 + tx;
        if (r < R && c < C) tile[j][tx] = in[(size_t)r * C + c];
    }
    __syncthreads();
    for (int j = ty; j < 32; j += 8) {
        int c = c0 + j, r = r0 + tx;
        if (r < R && c < C) outp[(size_t)c * R + r] = f2bf(tile[tx][j]);
    }
}

// ---------------- GEMM: C[M][N] = relu(A[M][K] @ Bt[N][K]^T + bias ...) ----
// 128x256 tile, BK=64, 8 waves (2x4), per-wave 64x64 via 4x4 16x16x32 frags.
// A operand: lane-private register fragments, double-buffered (aR0/aR1), prefetched
//   one K-tile ahead as plain global loads -> stay in flight across both barriers.
// B operand: global_load_lds into 32KB XOR-swizzled LDS (round-5/7 proven path).
// Sync per tile: vmcnt(8) (= keep the 8 A-prefetch loads in flight, drain B(4) +
//   prior A(8)) + raw s_barrier; second raw s_barrier after MFMA protects lB.
// XCD group-swizzle (round-6 proven). mode 0 plain / 1 L0 / 2 head1.
__global__ __launch_bounds__(512, 3) void gemm_bias_relu(
    const ushort* __restrict__ A, const ushort* __restrict__ Bt,
    const float* __restrict__ bias, ushort* __restrict__ C,
    int N, int K, const int* __restrict__ scal,
    const float* __restrict__ rolerows, int mode) {
    const int nb = N >> 8;
    const int xcd = blockIdx.x & 7, slot = blockIdx.x >> 3;
    const int wgid = ((slot / nb) * 8 + xcd) * nb + (slot % nb);
    const int brow = wgid / nb;
    const int bcol = wgid % nb;
    const int base1 = scal[4];
    const int mpad = scal[6];
    if (brow * 128 >= mpad) return;

    if (mode == 2) {
        int rt = (brow * 128 >= base1) ? 1 : 0;
        Bt += (size_t)rt * 512 * 1024;
        bias += rt * 512;
    }

    __shared__ __align__(16) ushort lB[256 * 64];   // 32 KB

    const int tid = threadIdx.x;
    const int w = tid >> 6;
    const int L = tid & 63;
    const int wr = w >> 2, wc = w & 3;
    const int fr = L & 15;
    const int g = L >> 4;
    const int rsw = (fr & 7) << 4;
    const int crow4 = g << 2;

    const int subrow = L >> 3;
    const int srcofs = ((L & 7) ^ subrow) << 3;
    const int bRow = bcol * 256 + (w << 5) + subrow;

    // A fragment base: row = brow*128 + wr*64 + m*16 + fr, col = kt*64 + kk*32 + g*8
    const ushort* aBase = A + (size_t)(brow * 128 + (wr << 6) + fr) * K + (g << 3);

    f32x4 acc[4][4];
#pragma unroll
    for (int i = 0; i < 4; i++)
#pragma unroll
        for (int j = 0; j < 4; j++) acc[i][j] = (f32x4){0.f, 0.f, 0.f, 0.f};

    bf16x8 aR0[2][4], aR1[2][4];   // static names only (rule #20)

#define LOADA(DST, KT) do { \
    const ushort* ap_ = aBase + ((size_t)(KT) << 6); \
    _Pragma("unroll") for (int kk_ = 0; kk_ < 2; kk_++) \
    _Pragma("unroll") for (int m_ = 0; m_ < 4; m_++) \
        DST[kk_][m_] = *(const bf16x8*)(ap_ + (size_t)(m_ << 4) * K + (kk_ << 5)); \
} while (0)

#define STAGEB(KT) do { \
    const ushort* gB_ = Bt + (size_t)bRow * K + ((size_t)(KT) << 6) + srcofs; \
    _Pragma("unroll") for (int j_ = 0; j_ < 4; j_++) \
        __builtin_amdgcn_global_load_lds( \
            (const __attribute__((address_space(1))) void*)(gB_ + (size_t)(8 * j_) * K), \
            (__attribute__((address_space(3))) void*)(&lB[((w << 5) + (j_ << 3)) << 6]), \
            16, 0, 0); \
} while (0)

#define SYNC_IN() do { \
    asm volatile("s_waitcnt vmcnt(8)" ::: "memory"); \
    __builtin_amdgcn_sched_barrier(0); \
    __builtin_amdgcn_s_barrier(); \
    __builtin_amdgcn_sched_barrier(0); \
} while (0)

#define SYNC_OUT() do { \
    __builtin_amdgcn_sched_barrier(0); \
    __builtin_amdgcn_s_barrier(); \
    __builtin_amdgcn_sched_barrier(0); \
} while (0)

#define COMPUTE(AREG) do { \
    _Pragma("unroll") for (int kk_ = 0; kk_ < 2; kk_++) { \
        const int cbs_ = ((kk_ << 6) + (g << 4)) ^ rsw; \
        bf16x8 bfr_[4]; \
        _Pragma("unroll") for (int n_ = 0; n_ < 4; n_++) \
            bfr_[n_] = *(const bf16x8*)((const char*)lB + ((wc << 6) + (n_ << 4) + fr) * 128 + cbs_); \
        _Pragma("unroll") for (int m_ = 0; m_ < 4; m_++) \
        _Pragma("unroll") for (int n_ = 0; n_ < 4; n_++) \
            acc[m_][n_] = __builtin_amdgcn_mfma_f32_16x16x32_bf16(AREG[kk_][m_], bfr_[n_], acc[m_][n_], 0, 0, 0); \
    } \
} while (0)

    const int nk = K >> 6;                 // 2 (L0) or 16 — always even
    LOADA(aR0, 0);
    for (int kt = 0; kt < nk; kt += 2) {
        // body A: compute tile kt from aR0, prefetch kt+1 into aR1
        STAGEB(kt);
        LOADA(aR1, (kt + 1 < nk) ? kt + 1 : nk - 1);
        SYNC_IN();
        COMPUTE(aR0);
        SYNC_OUT();
        // body B: compute tile kt+1 from aR1, prefetch kt+2 into aR0
        STAGEB(kt + 1);
        LOADA(aR0, (kt + 2 < nk) ? kt + 2 : nk - 1);
        SYNC_IN();
        COMPUTE(aR1);
        SYNC_OUT();
    }
#undef LOADA
#undef STAGEB
#undef SYNC_IN
#undef SYNC_OUT
#undef COMPUTE

#pragma unroll
    for (int m = 0; m < 4; m++) {
        const int rowb = brow * 128 + (wr << 6) + (m << 4) + crow4;
#pragma unroll
        for (int j = 0; j < 4; j++) {
            const int r = rowb + j;
            const int role = (r >= base1) ? 1 : 0;
#pragma unroll
            for (int n = 0; n < 4; n++) {
                const int col = bcol * 256 + (wc << 6) + (n << 4) + fr;
                float v = acc[m][n][j] + bias[col];
                if (mode == 1) v += rolerows[(size_t)role * N + col];
                v = v > 0.f ? v : 0.f;
                C[(size_t)r * N + col] = f2bf(v);
            }
        }
    }
}

// ---------------- final: head2 + tanh + gaussian logprob, wave per slot ----------------
__global__ __launch_bounds__(256) void head_final(
    const ushort* __restrict__ z,
    const float* __restrict__ actions,
    const int* __restrict__ slot2tok, const int* __restrict__ scal,
    const ushort* __restrict__ hW2t,
    const float* __restrict__ hb2,
    const float* __restrict__ log_stds,
    float* __restrict__ out) {
    const int lane = threadIdx.x & 63;
    const int s = blockIdx.x * (blockDim.x >> 6) + (threadIdx.x >> 6);
    const int c0 = scal[0], base1 = scal[4], mact = scal[5];
    if (s >= mact) return;
    if (s >= c0 && s < base1) return;  // pad gap
    const int r = (s >= base1) ? 1 : 0;
    const int t = slot2tok[s];

    const ushort* zp = z + (size_t)s * 512;
    uint4 zr = ((const uint4*)zp)[lane];
    unsigned zz[4] = {zr.x, zr.y, zr.z, zr.w};
    float zv[8];
#pragma unroll
    for (int i = 0; i < 4; i++) {
        zv[2 * i]     = bf2f((ushort)(zz[i] & 0xffffu));
        zv[2 * i + 1] = bf2f((ushort)(zz[i] >> 16));
    }
    float dk[8];
#pragma unroll
    for (int k = 0; k < 8; k++) {
        const ushort* wp = hW2t + r * 4096 + k * 512;
        uint4 wv = ((const uint4*)wp)[lane];
        unsigned ww[4] = {wv.x, wv.y, wv.z, wv.w};
        float sacc = 0.f;
#pragma unroll
        for (int i = 0; i < 4; i++) {
            sacc += zv[2 * i]     * bf2f((ushort)(ww[i] & 0xffffu));
            sacc += zv[2 * i + 1] * bf2f((ushort)(ww[i] >> 16));
        }
        dk[k] = sacc;
    }
#pragma unroll
    for (int off = 32; off >= 1; off >>= 1) {
#pragma unroll
        for (int k = 0; k < 8; k++) dk[k] += __shfl_xor(dk[k], off, 64);
    }
    if (lane == 0) {
        float lp = 0.f;
#pragma unroll
        for (int k = 0; k < 8; k++) {
            float mean = tanhf(dk[k] + hb2[r * 8 + k]);
            float ls = log_stds[r * 8 + k];
            float diff = (actions[(size_t)t * 8 + k] - mean) * expf(-ls);
            lp += -0.5f * diff * diff - ls - 0.5f * LOG_2PI_F;
        }
        out[t] = lp;
    }
}

extern "C" void kernel_launch(void* const* d_in, const int* in_sizes, int n_in,
                              void* d_out, int out_size, void* d_ws, size_t ws_size,
                              hipStream_t stream) {
    const float* obs      = (const float*)d_in[0];
    const int*   role_ids = (const int*)d_in[1];
    const float* actions  = (const float*)d_in[2];
    const float* W0       = (const float*)d_in[3];
    const float* b0       = (const float*)d_in[4];
    const float* W1       = (const float*)d_in[5];
    const float* b1       = (const float*)d_in[6];
    const float* W2       = (const float*)d_in[7];
    const float* b2       = (const float*)d_in[8];
    const float* hW1      = (const float*)d_in[9];
    const float* hb1      = (const float*)d_in[10];
    const float* hW2      = (const float*)d_in[11];
    const float* hb2      = (const float*)d_in[12];
    const float* log_stds = (const float*)d_in[13];
    float* out = (float*)d_out;

    const int T = 32768, H = 1024, OB = 128, H2 = 512;

    char* ws = (char*)d_ws;
    int*    scal = (int*)ws;    ws += 256;
    int* slot2tok = (int*)ws;   ws += (size_t)T * 4;
    ushort* obsb = (ushort*)ws; ws += (size_t)T * OB * 2;
    ushort* W0t  = (ushort*)ws; ws += (size_t)H * OB * 2;
    ushort* W1t  = (ushort*)ws; ws += (size_t)H * H * 2;
    ushort* W2t  = (ushort*)ws; ws += (size_t)H * H * 2;
    ushort* hW1t = (ushort*)ws; ws += (size_t)H * H * 2;
    ushort* hW2t = (ushort*)ws; ws += (size_t)2 * 8 * H2 * 2;
    ushort* bufA = (ushort*)ws; ws += (size_t)T * H * 2;
    ushort* bufB = (ushort*)ws;

    prep_all<<<3360, 256, 0, stream>>>(obs, role_ids, W0, W1, W2, hW1, hW2,
                                       obsb, W0t, W1t, W2t, hW1t, hW2t,
                                       slot2tok, scal, out);

    const int gridH = (T / 128) * (H / 256);   // 1024
    const int gridZ = (T / 128) * (H2 / 256);  // 512
    gemm_bias_relu<<<gridH, 512, 0, stream>>>(obsb, W0t, b0, bufA, H, OB, scal, W0 + 128 * H, 1);
    gemm_bias_relu<<<gridH, 512, 0, stream>>>(bufA, W1t, b1, bufB, H, H, scal, nullptr, 0);
    gemm_bias_relu<<<gridH, 512, 0, stream>>>(bufB, W2t, b2, bufA, H, H, scal, nullptr, 0);
    gemm_bias_relu<<<gridZ, 512, 0, stream>>>(bufA, hW1t, hb1, bufB, H2, H, scal, nullptr, 2);

    head_final<<<T / 4, 256, 0, stream>>>(bufB, actions, slot2tok, scal, hW2t, hb2, log_stds, out);
}

// Round 11
// 292.472 us; speedup vs baseline: 1.8241x; 1.8241x over previous
//
#include <hip/hip_runtime.h>
#include <math.h>

typedef __attribute__((ext_vector_type(4))) float f32x4;
typedef __bf16 bf16x8 __attribute__((ext_vector_type(8)));

#define LOG_2PI_F 1.8378770664093453f

// scal layout (ints): [0]=cnt0 [1]=cnt1 [4]=base1 [5]=mact [6]=mpad

__device__ static inline ushort f2bf(float f) {
    union { float f; unsigned u; } c; c.f = f;
    unsigned u = c.u;
    unsigned r = (u + 0x7FFFu + ((u >> 16) & 1u)) >> 16;
    return (ushort)r;
}
__device__ static inline float bf2f(ushort h) {
    union { unsigned u; float f; } c; c.u = ((unsigned)h) << 16;
    return c.f;
}

// ---------------- compaction (ballot/scan, no contended atomics) ----------------
__global__ void count_blocks(const int* __restrict__ role_ids,
                             int* __restrict__ blk0, int* __restrict__ blk1, int T) {
    int i = blockIdx.x * 256 + threadIdx.x;
    int r = (i < T) ? role_ids[i] : 3;
    unsigned long long b0 = __ballot(r == 0);
    unsigned long long b1 = __ballot(r == 1);
    __shared__ int s0[4], s1[4];
    int lane = threadIdx.x & 63, w = threadIdx.x >> 6;
    if (lane == 0) { s0[w] = __popcll(b0); s1[w] = __popcll(b1); }
    __syncthreads();
    if (threadIdx.x == 0) {
        blk0[blockIdx.x] = s0[0] + s0[1] + s0[2] + s0[3];
        blk1[blockIdx.x] = s1[0] + s1[1] + s1[2] + s1[3];
    }
}

// 1 block x 128 threads: Hillis-Steele exclusive scan over NB=128 block counts
__global__ void scan_blocks(const int* __restrict__ blk0, const int* __restrict__ blk1,
                            int* __restrict__ off0, int* __restrict__ off1,
                            int* __restrict__ scal, int NB) {
    __shared__ int a0[128], a1[128];
    int t = threadIdx.x;
    int v0 = blk0[t], v1 = blk1[t];
    a0[t] = v0; a1[t] = v1;
    __syncthreads();
    for (int d = 1; d < 128; d <<= 1) {
        int y0 = (t >= d) ? a0[t - d] : 0;
        int y1 = (t >= d) ? a1[t - d] : 0;
        __syncthreads();
        a0[t] += y0; a1[t] += y1;
        __syncthreads();
    }
    off0[t] = a0[t] - v0;     // exclusive
    off1[t] = a1[t] - v1;
    if (t == 127) {
        int a = a0[127], b = a1[127];
        int base1 = (a + 127) & ~127;
        int mact = base1 + b;
        int mpad = (mact + 127) & ~127;
        scal[0] = a; scal[1] = b;
        scal[4] = base1; scal[5] = mact; scal[6] = mpad;
    }
}

__global__ void assign_slots(const int* __restrict__ role_ids,
                             const int* __restrict__ off0, const int* __restrict__ off1,
                             const int* __restrict__ scal,
                             int* __restrict__ slot2tok, int T) {
    int i = blockIdx.x * 256 + threadIdx.x;
    int r = (i < T) ? role_ids[i] : 3;
    unsigned long long b0 = __ballot(r == 0);
    unsigned long long b1 = __ballot(r == 1);
    __shared__ int s0[4], s1[4];
    int lane = threadIdx.x & 63, w = threadIdx.x >> 6;
    if (lane == 0) { s0[w] = __popcll(b0); s1[w] = __popcll(b1); }
    __syncthreads();
    int w0 = 0, w1 = 0;
    for (int j = 0; j < 4; j++) {
        if (j < w) { w0 += s0[j]; w1 += s1[j]; }
    }
    unsigned long long lt = (lane == 0) ? 0ull
                         : ((lane == 63) ? 0x7FFFFFFFFFFFFFFFull : ((1ull << lane) - 1));
    if (r == 0) {
        int slot = off0[blockIdx.x] + w0 + (int)__popcll(b0 & lt);
        slot2tok[slot] = i;
    } else if (r == 1) {
        int slot = scal[4] + off1[blockIdx.x] + w1 + (int)__popcll(b1 & lt);
        slot2tok[slot] = i;
    }
}

// wave per slot: gather obs rows into compacted bf16 [slot][128]; zero pad/gap rows
__global__ void gather_obs(const float* __restrict__ obs, const int* __restrict__ slot2tok,
                           const int* __restrict__ scal, ushort* __restrict__ obsb) {
    int lane = threadIdx.x & 63;
    int s = blockIdx.x * (blockDim.x >> 6) + (threadIdx.x >> 6);
    int c0 = scal[0], base1 = scal[4], mact = scal[5], mpad = scal[6];
    if (s >= mpad) return;
    ushort2* dst = (ushort2*)(obsb + (size_t)s * 128);
    bool real = (s < c0) || (s >= base1 && s < mact);
    if (!real) { dst[lane] = (ushort2){0, 0}; return; }
    int t = slot2tok[s];
    float2 v = ((const float2*)(obs + (size_t)t * 128))[lane];
    dst[lane] = (ushort2){f2bf(v.x), f2bf(v.y)};
}

// ---------------- prep: all weight transposes batched in one launch ----------------
__global__ void transpose_all(const float* __restrict__ W0, const float* __restrict__ W1,
                              const float* __restrict__ W2, const float* __restrict__ hW1,
                              const float* __restrict__ hW2,
                              ushort* __restrict__ W0t, ushort* __restrict__ W1t,
                              ushort* __restrict__ W2t, ushort* __restrict__ hW1t,
                              ushort* __restrict__ hW2t) {
    __shared__ float tile[32][33];
    int id = blockIdx.x;
    const float* in; ushort* out; int R, C, t;
    if (id < 128)       { in = W0;              out = W0t;              R = 128;  C = 1024; t = id; }
    else if (id < 1152) { in = W1;              out = W1t;              R = 1024; C = 1024; t = id - 128; }
    else if (id < 2176) { in = W2;              out = W2t;              R = 1024; C = 1024; t = id - 1152; }
    else if (id < 2688) { in = hW1;             out = hW1t;             R = 1024; C = 512;  t = id - 2176; }
    else if (id < 3200) { in = hW1 + 1024*512;  out = hW1t + 512*1024;  R = 1024; C = 512;  t = id - 2688; }
    else if (id < 3216) { in = hW2;             out = hW2t;             R = 512;  C = 8;    t = id - 3200; }
    else                { in = hW2 + 512*8;     out = hW2t + 8*512;     R = 512;  C = 8;    t = id - 3216; }
    int tX = (C + 31) >> 5;
    int c0 = (t % tX) << 5, r0 = (t / tX) << 5;
    for (int j = threadIdx.y; j < 32; j += 8) {
        int r = r0 + j, c = c0 + threadIdx.x;
        if (r < R && c < C) tile[j][threadIdx.x] = in[(size_t)r * C + c];
    }
    __syncthreads();
    for (int j = threadIdx.y; j < 32; j += 8) {
        int c = c0 + j, r = r0 + threadIdx.x;
        if (r < R && c < C) out[(size_t)c * R + r] = f2bf(tile[threadIdx.x][j]);
    }
}

// ---------------- GEMM: C[M][N] = relu(A[M][K] @ Bt[N][K]^T + bias ...) ----
// 128x256 tile, BK=64, 512 threads = 8 waves (2x4), per-wave 64x64 via 4x4 16x16x32 frags.
// Single-buffer LDS 48KB (3 blocks/CU — round-5 proven), XOR-swizzled (conflicts=0).
// XCD group-swizzle (round-6 proven: FETCH 92->39MB): same-brow col-blocks on one XCD.
// mode 0: plain.  mode 1: L0 (+ per-role W0 row).
__global__ __launch_bounds__(512, 4) void gemm_bias_relu(
    const ushort* __restrict__ A, const ushort* __restrict__ Bt,
    const float* __restrict__ bias, ushort* __restrict__ C,
    int N, int K, const int* __restrict__ scal,
    const float* __restrict__ rolerows, int mode) {
    const int nb = N >> 8;                 // 256-wide col tiles
    const int xcd = blockIdx.x & 7, slot = blockIdx.x >> 3;
    const int wgid = ((slot / nb) * 8 + xcd) * nb + (slot % nb);
    const int brow = wgid / nb;
    const int bcol = wgid % nb;
    const int base1 = scal[4];
    const int mpad = scal[6];
    if (brow * 128 >= mpad) return;

    __shared__ __align__(16) ushort lA[128 * 64];   // 16 KB
    __shared__ __align__(16) ushort lB[256 * 64];   // 32 KB

    const int tid = threadIdx.x;
    const int w = tid >> 6;                // wave 0..7
    const int L = tid & 63;
    const int wr = w >> 2, wc = w & 3;     // 2x4 wave grid
    const int fr = L & 15;
    const int g = L >> 4;                  // k-group 0..3
    const int rsw = (fr & 7) << 4;         // read-side byte XOR
    const int crow4 = g << 2;

    // staging geometry (round-5 verified)
    const int subrow = L >> 3;                       // 0..7 within 8-row chunk
    const int srcofs = ((L & 7) ^ subrow) << 3;      // element offset (inverse swizzle)
    const int aRow = brow * 128 + (w << 4) + subrow; // + 8j
    const int bRow = bcol * 256 + (w << 5) + subrow; // + 8j

    f32x4 acc[4][4];
#pragma unroll
    for (int i = 0; i < 4; i++)
#pragma unroll
        for (int j = 0; j < 4; j++) acc[i][j] = (f32x4){0.f, 0.f, 0.f, 0.f};

    const int nk = K >> 6;
    for (int kt = 0; kt < nk; ++kt) {
        const int k0 = kt << 6;
        const ushort* gA = A + (size_t)aRow * K + k0 + srcofs;
#pragma unroll
        for (int j = 0; j < 2; j++) {
            __builtin_amdgcn_global_load_lds(
                (const __attribute__((address_space(1))) void*)(gA + (size_t)(8 * j) * K),
                (__attribute__((address_space(3))) void*)(&lA[((w << 4) + (j << 3)) << 6]),
                16, 0, 0);
        }
        const ushort* gB = Bt + (size_t)bRow * K + k0 + srcofs;
#pragma unroll
        for (int j = 0; j < 4; j++) {
            __builtin_amdgcn_global_load_lds(
                (const __attribute__((address_space(1))) void*)(gB + (size_t)(8 * j) * K),
                (__attribute__((address_space(3))) void*)(&lB[((w << 5) + (j << 3)) << 6]),
                16, 0, 0);
        }
        __syncthreads();

#pragma unroll
        for (int kk = 0; kk < 2; kk++) {
            const int cbs = ((kk << 6) + (g << 4)) ^ rsw;
            bf16x8 af[4], bfr[4];
#pragma unroll
            for (int m = 0; m < 4; m++)
                af[m] = *(const bf16x8*)((const char*)lA + ((wr << 6) + (m << 4) + fr) * 128 + cbs);
#pragma unroll
            for (int n = 0; n < 4; n++)
                bfr[n] = *(const bf16x8*)((const char*)lB + ((wc << 6) + (n << 4) + fr) * 128 + cbs);
#pragma unroll
            for (int m = 0; m < 4; m++)
#pragma unroll
                for (int n = 0; n < 4; n++)
                    acc[m][n] = __builtin_amdgcn_mfma_f32_16x16x32_bf16(af[m], bfr[n], acc[m][n], 0, 0, 0);
        }
        __syncthreads();
    }

#pragma unroll
    for (int m = 0; m < 4; m++) {
        const int rowb = brow * 128 + (wr << 6) + (m << 4) + crow4;
#pragma unroll
        for (int j = 0; j < 4; j++) {
            const int r = rowb + j;
            const int role = (r >= base1) ? 1 : 0;
#pragma unroll
            for (int n = 0; n < 4; n++) {
                const int col = bcol * 256 + (wc << 6) + (n << 4) + fr;
                float v = acc[m][n][j] + bias[col];
                if (mode == 1) v += rolerows[(size_t)role * N + col];
                v = v > 0.f ? v : 0.f;
                C[(size_t)r * N + col] = f2bf(v);
            }
        }
    }
}

// ---------------- head1 GEMM: 128x128 tile, BK=64, 256 threads = 4 waves (2x2) ----------
// Same per-wave mix as the 256-wide kernel (32 MFMA + 8 staging loads per K-tile) but
// LDS 32KB -> 5 blocks/CU: fixes head1's residency starvation (344-block grid at BN=256
// gave ~1.3 blocks/CU -> no inter-block overlap -> 59us for half a mid-GEMM's FLOPs).
// Role handling: row tiles are role-pure (base1%128==0); Bt/bias offset by tile role.
__global__ __launch_bounds__(256, 5) void gemm_head1(
    const ushort* __restrict__ A, const ushort* __restrict__ Bt,
    const float* __restrict__ bias, ushort* __restrict__ C,
    const int* __restrict__ scal) {
    const int N = 512, K = 1024;
    const int nb = 4;                      // 512 / 128
    const int xcd = blockIdx.x & 7, slot = blockIdx.x >> 3;
    const int wgid = ((slot / nb) * 8 + xcd) * nb + (slot % nb);
    const int brow = wgid / nb;
    const int bcol = wgid % nb;
    const int base1 = scal[4];
    const int mpad = scal[6];
    if (brow * 128 >= mpad) return;

    const int rt = (brow * 128 >= base1) ? 1 : 0;
    Bt += (size_t)rt * 512 * 1024;
    bias += rt * 512;

    __shared__ __align__(16) ushort lA[128 * 64];   // 16 KB
    __shared__ __align__(16) ushort lB[128 * 64];   // 16 KB

    const int tid = threadIdx.x;
    const int w = tid >> 6;                // wave 0..3
    const int L = tid & 63;
    const int wr = w >> 1, wc = w & 1;     // 2x2 wave grid
    const int fr = L & 15;
    const int g = L >> 4;
    const int rsw = (fr & 7) << 4;
    const int crow4 = g << 2;

    const int subrow = L >> 3;
    const int srcofs = ((L & 7) ^ subrow) << 3;
    const int aRow = brow * 128 + (w << 5) + subrow;   // each wave: 32 rows (+8j)
    const int bRow = bcol * 128 + (w << 5) + subrow;

    f32x4 acc[4][4];
#pragma unroll
    for (int i = 0; i < 4; i++)
#pragma unroll
        for (int j = 0; j < 4; j++) acc[i][j] = (f32x4){0.f, 0.f, 0.f, 0.f};

    const int nk = K >> 6;   // 16
    for (int kt = 0; kt < nk; ++kt) {
        const int k0 = kt << 6;
        const ushort* gA = A + (size_t)aRow * K + k0 + srcofs;
        const ushort* gB = Bt + (size_t)bRow * K + k0 + srcofs;
#pragma unroll
        for (int j = 0; j < 4; j++) {
            __builtin_amdgcn_global_load_lds(
                (const __attribute__((address_space(1))) void*)(gA + (size_t)(8 * j) * K),
                (__attribute__((address_space(3))) void*)(&lA[((w << 5) + (j << 3)) << 6]),
                16, 0, 0);
            __builtin_amdgcn_global_load_lds(
                (const __attribute__((address_space(1))) void*)(gB + (size_t)(8 * j) * K),
                (__attribute__((address_space(3))) void*)(&lB[((w << 5) + (j << 3)) << 6]),
                16, 0, 0);
        }
        __syncthreads();

#pragma unroll
        for (int kk = 0; kk < 2; kk++) {
            const int cbs = ((kk << 6) + (g << 4)) ^ rsw;
            bf16x8 af[4], bfr[4];
#pragma unroll
            for (int m = 0; m < 4; m++)
                af[m] = *(const bf16x8*)((const char*)lA + ((wr << 6) + (m << 4) + fr) * 128 + cbs);
#pragma unroll
            for (int n = 0; n < 4; n++)
                bfr[n] = *(const bf16x8*)((const char*)lB + ((wc << 6) + (n << 4) + fr) * 128 + cbs);
#pragma unroll
            for (int m = 0; m < 4; m++)
#pragma unroll
                for (int n = 0; n < 4; n++)
                    acc[m][n] = __builtin_amdgcn_mfma_f32_16x16x32_bf16(af[m], bfr[n], acc[m][n], 0, 0, 0);
        }
        __syncthreads();
    }

#pragma unroll
    for (int m = 0; m < 4; m++) {
        const int rowb = brow * 128 + (wr << 6) + (m << 4) + crow4;
#pragma unroll
        for (int j = 0; j < 4; j++) {
            const int r = rowb + j;
#pragma unroll
            for (int n = 0; n < 4; n++) {
                const int col = bcol * 128 + (wc << 6) + (n << 4) + fr;
                float v = acc[m][n][j] + bias[col];
                v = v > 0.f ? v : 0.f;
                C[(size_t)r * N + col] = f2bf(v);
            }
        }
    }
}

// ---------------- final: head2 + tanh + gaussian logprob, wave per slot ----------------
__global__ __launch_bounds__(256) void head_final(
    const ushort* __restrict__ z,       // [slot][512] bf16 (own-role z)
    const float* __restrict__ actions,  // [T][8]
    const int* __restrict__ slot2tok, const int* __restrict__ scal,
    const ushort* __restrict__ hW2t,    // [2][8][512] bf16
    const float* __restrict__ hb2,      // [2][8]
    const float* __restrict__ log_stds, // [2][8]
    float* __restrict__ out) {
    const int lane = threadIdx.x & 63;
    const int s = blockIdx.x * (blockDim.x >> 6) + (threadIdx.x >> 6);
    const int c0 = scal[0], base1 = scal[4], mact = scal[5];
    if (s >= mact) return;
    if (s >= c0 && s < base1) return;  // pad gap
    const int r = (s >= base1) ? 1 : 0;
    const int t = slot2tok[s];

    const ushort* zp = z + (size_t)s * 512;
    uint4 zr = ((const uint4*)zp)[lane];
    unsigned zz[4] = {zr.x, zr.y, zr.z, zr.w};
    float zv[8];
#pragma unroll
    for (int i = 0; i < 4; i++) {
        zv[2 * i]     = bf2f((ushort)(zz[i] & 0xffffu));
        zv[2 * i + 1] = bf2f((ushort)(zz[i] >> 16));
    }
    float dk[8];
#pragma unroll
    for (int k = 0; k < 8; k++) {
        const ushort* wp = hW2t + r * 4096 + k * 512;
        uint4 wv = ((const uint4*)wp)[lane];
        unsigned ww[4] = {wv.x, wv.y, wv.z, wv.w};
        float sacc = 0.f;
#pragma unroll
        for (int i = 0; i < 4; i++) {
            sacc += zv[2 * i]     * bf2f((ushort)(ww[i] & 0xffffu));
            sacc += zv[2 * i + 1] * bf2f((ushort)(ww[i] >> 16));
        }
        dk[k] = sacc;
    }
#pragma unroll
    for (int off = 32; off >= 1; off >>= 1) {
#pragma unroll
        for (int k = 0; k < 8; k++) dk[k] += __shfl_xor(dk[k], off, 64);
    }
    if (lane == 0) {
        float lp = 0.f;
#pragma unroll
        for (int k = 0; k < 8; k++) {
            float mean = tanhf(dk[k] + hb2[r * 8 + k]);
            float ls = log_stds[r * 8 + k];
            float diff = (actions[(size_t)t * 8 + k] - mean) * expf(-ls);
            lp += -0.5f * diff * diff - ls - 0.5f * LOG_2PI_F;
        }
        out[t] = lp;
    }
}

extern "C" void kernel_launch(void* const* d_in, const int* in_sizes, int n_in,
                              void* d_out, int out_size, void* d_ws, size_t ws_size,
                              hipStream_t stream) {
    const float* obs      = (const float*)d_in[0];
    const int*   role_ids = (const int*)d_in[1];
    const float* actions  = (const float*)d_in[2];
    const float* W0       = (const float*)d_in[3];
    const float* b0       = (const float*)d_in[4];
    const float* W1       = (const float*)d_in[5];
    const float* b1       = (const float*)d_in[6];
    const float* W2       = (const float*)d_in[7];
    const float* b2       = (const float*)d_in[8];
    const float* hW1      = (const float*)d_in[9];
    const float* hb1      = (const float*)d_in[10];
    const float* hW2      = (const float*)d_in[11];
    const float* hb2      = (const float*)d_in[12];
    const float* log_stds = (const float*)d_in[13];
    float* out = (float*)d_out;

    const int T = 32768, H = 1024, OB = 128, H2 = 512;
    const int NB = T / 256;  // 128 blocks

    char* ws = (char*)d_ws;
    int*    scal = (int*)ws;    ws += 256;
    int* blk0 = (int*)ws;       ws += NB * 4;
    int* blk1 = (int*)ws;       ws += NB * 4;
    int* off0 = (int*)ws;       ws += NB * 4;
    int* off1 = (int*)ws;       ws += NB * 4;
    int* slot2tok = (int*)ws;   ws += (size_t)T * 4;            // 128 KB
    ushort* obsb = (ushort*)ws; ws += (size_t)T * OB * 2;       // 8 MB
    ushort* W0t  = (ushort*)ws; ws += (size_t)H * OB * 2;       // 256 KB
    ushort* W1t  = (ushort*)ws; ws += (size_t)H * H * 2;        // 2 MB
    ushort* W2t  = (ushort*)ws; ws += (size_t)H * H * 2;        // 2 MB
    ushort* hW1t = (ushort*)ws; ws += (size_t)H * H * 2;        // 2 MB (both roles)
    ushort* hW2t = (ushort*)ws; ws += (size_t)2 * 8 * H2 * 2;   // 16 KB
    ushort* bufA = (ushort*)ws; ws += (size_t)T * H * 2;        // 64 MB (h0, then h2)
    ushort* bufB = (ushort*)ws;                                 // 64 MB (h1, then z)

    hipMemsetAsync(out, 0, (size_t)T * 4, stream);   // prey tokens -> 0

    count_blocks<<<NB, 256, 0, stream>>>(role_ids, blk0, blk1, T);
    scan_blocks<<<1, 128, 0, stream>>>(blk0, blk1, off0, off1, scal, NB);
    assign_slots<<<NB, 256, 0, stream>>>(role_ids, off0, off1, scal, slot2tok, T);
    gather_obs<<<T / 4, 256, 0, stream>>>(obs, slot2tok, scal, obsb);

    transpose_all<<<3232, dim3(32, 8), 0, stream>>>(W0, W1, W2, hW1, hW2,
                                                    W0t, W1t, W2t, hW1t, hW2t);

    // GEMMs over compacted rows (blocks past mpad early-exit)
    const int gridH = (T / 128) * (H / 256);   // 1024, 128x256 tiles
    const int gridZ = (T / 128) * 4;           // 1024, 128x128 tiles (head1)
    gemm_bias_relu<<<gridH, 512, 0, stream>>>(obsb, W0t, b0, bufA, H, OB, scal, W0 + 128 * H, 1);
    gemm_bias_relu<<<gridH, 512, 0, stream>>>(bufA, W1t, b1, bufB, H, H, scal, nullptr, 0);
    gemm_bias_relu<<<gridH, 512, 0, stream>>>(bufB, W2t, b2, bufA, H, H, scal, nullptr, 0);
    gemm_head1<<<gridZ, 256, 0, stream>>>(bufA, hW1t, hb1, bufB, scal);

    head_final<<<T / 4, 256, 0, stream>>>(bufB, actions, slot2tok, scal, hW2t, hb2, log_stds, out);
}